// Round 8
// baseline (3682.593 us; speedup 1.0000x reference)
//
#include <hip/hip_runtime.h>
#include <hip/hip_bf16.h>
#include <stdint.h>
#include <type_traits>

typedef unsigned short u16;
typedef __bf16 bf16x8 __attribute__((ext_vector_type(8)));
typedef float f32x4 __attribute__((ext_vector_type(4)));

#define M_TOT 8192   // B*S
#define N_TOT 4096   // reduction dim
#define K_TOT 4096   // output dim
#define BM 256
#define BN 256
#define BK 64
#define NT 64        // N_TOT / BK

// LDS geometry in u16 elements: [slot][A:2 halves | B:2 halves][128][64]
#define HALF_EL 8192     // 128 rows * 64 cols
#define B_OFF   16384
#define SLOT_EL 32768    // 64 KiB per slot

template <int V> using ic = std::integral_constant<int, V>;
template <bool V> using bc = std::integral_constant<bool, V>;

__device__ __forceinline__ u16 f2bf(float f) {
    union { float f; uint32_t u; } v; v.f = f;
    uint32_t u = v.u;
    return (u16)((u + 0x7fffu + ((u >> 16) & 1u)) >> 16);
}

// ---- pre-pass 1: x fp32 -> bf16 ----------------------------------------------
__global__ __launch_bounds__(256) void cvt_x_kernel(const float* __restrict__ x,
                                                    u16* __restrict__ xb) {
    const int i = blockIdx.x * blockDim.x + threadIdx.x;
    const float4* p = (const float4*)x + (size_t)i * 2;
    float4 v0 = p[0], v1 = p[1];
    uint4 o;
    o.x = (uint32_t)f2bf(v0.x) | ((uint32_t)f2bf(v0.y) << 16);
    o.y = (uint32_t)f2bf(v0.z) | ((uint32_t)f2bf(v0.w) << 16);
    o.z = (uint32_t)f2bf(v1.x) | ((uint32_t)f2bf(v1.y) << 16);
    o.w = (uint32_t)f2bf(v1.z) | ((uint32_t)f2bf(v1.w) << 16);
    *((uint4*)(xb + (size_t)i * 8)) = o;
}

// ---- pre-pass 2: dequantize W_q -> bf16 --------------------------------------
__global__ __launch_bounds__(256) void deq_w_kernel(const int* __restrict__ wq,
                                                    const float* __restrict__ scales,
                                                    const float* __restrict__ zeros,
                                                    const float* __restrict__ mu1,
                                                    const float* __restrict__ mu2,
                                                    u16* __restrict__ wb) {
    const int i = blockIdx.x * blockDim.x + threadIdx.x;
    const int k  = i >> 9;
    const int n0 = (i & 511) << 3;
    const int g  = n0 >> 6;
    const float z  = zeros[k * 64 + g];
    const float sm = scales[k * 64 + g] * mu2[k];
    const int4* qp = (const int4*)(wq + (size_t)k * N_TOT + n0);
    int4 q0 = qp[0], q1 = qp[1];
    const float4* mp = (const float4*)(mu1 + n0);
    float4 u0 = mp[0], u1 = mp[1];
    uint4 o;
    o.x = (uint32_t)f2bf(((float)q0.x - z) * sm * u0.x) |
          ((uint32_t)f2bf(((float)q0.y - z) * sm * u0.y) << 16);
    o.y = (uint32_t)f2bf(((float)q0.z - z) * sm * u0.z) |
          ((uint32_t)f2bf(((float)q0.w - z) * sm * u0.w) << 16);
    o.z = (uint32_t)f2bf(((float)q1.x - z) * sm * u1.x) |
          ((uint32_t)f2bf(((float)q1.y - z) * sm * u1.y) << 16);
    o.w = (uint32_t)f2bf(((float)q1.z - z) * sm * u1.z) |
          ((uint32_t)f2bf(((float)q1.w - z) * sm * u1.w) << 16);
    *((uint4*)(wb + (size_t)k * N_TOT + n0)) = o;
}

// ---- main GEMM: 256x256, continuous-flow (no LDS drain, 1 barrier/K-tile) ----
// 8 waves (2M x 4N), per-wave out 128x64, BK=64, double-buffered LDS.
// Per tile t (slot s=t&1): stage all of t+1 into slot^1 (issued at tile top,
// ~1 tile of flight); read B1,A1 frags of slot s; 64 MFMA gray-code
// (p0=(0,0) uses frags read BEFORE the previous barrier); vmcnt(0) (drains
// only old stages); s_barrier; read-ahead next tile's A0,B0 from slot^1.
// NO explicit lgkmcnt anywhere: the compiler emits minimal counted waits, so
// LDS reads stay in flight underneath the MFMA clusters and across barriers.
// Liveness: tile t reads only slot s; stage(t+1->slot^1) issues after the
// barrier ending t-1, by which point every wave's slot^1 reads completed
// (in-wave lgkm gating before their MFMA consumers, all pre-barrier).
// Read-ahead touches slot^1 only after all waves' vmcnt(0)+barrier.
// LDS XOR swizzle (proven R2): physical col = logical ^ ((row&7)*8 elems);
// linear gload_lds dest + inverse-swizzled global source + swizzled ds_read.
__global__ __launch_bounds__(512, 2) void gemm_kernel(const u16* __restrict__ Xb,
                                                      const u16* __restrict__ Wb,
                                                      const float* __restrict__ bias,
                                                      float* __restrict__ out) {
    __shared__ __align__(16) u16 lds[2 * SLOT_EL];   // 128 KiB

    // XCD-bijective swizzle: nwg = 512, divisible by 8
    const int bid = blockIdx.x;
    const int cpx = gridDim.x >> 3;
    const int swz = (bid & 7) * cpx + (bid >> 3);
    const int bm = swz >> 4;    // 32 M-tiles
    const int bn = swz & 15;    // 16 out-tiles

    const int tid  = threadIdx.x;
    const int w    = tid >> 6;
    const int lane = tid & 63;
    const int wm = w >> 2, wn = w & 3;

    // staging: lane l, issue i covers LDS row (w*16 + i*8 + (l>>3)), physical
    // col (l&7)*16B; global col pre-swizzled: ((l&7)^(l>>3))*8 elems.
    const int scol = (((lane & 7) ^ (lane >> 3)) << 3);
    const u16* aT = Xb + (size_t)(bm * BM + w * 16 + (lane >> 3)) * N_TOT + scol;
    const u16* bT = Wb + (size_t)(bn * BN + w * 16 + (lane >> 3)) * N_TOT + scol;

    u16* const sdA = &lds[w * 1024];
    u16* const sdB = &lds[B_OFF + w * 1024];

    auto gload = [](const u16* s, u16* d) {
        __builtin_amdgcn_global_load_lds(
            (const __attribute__((address_space(1))) uint32_t*)s,
            (__attribute__((address_space(3))) uint32_t*)d, 16, 0, 0);
    };
    auto stA = [&](auto SlC, auto Hc, auto Dc) {
        const u16* s = aT + (size_t)(Hc.value * 128) * N_TOT + Dc.value;
        u16* d = sdA + SlC.value * SLOT_EL + Hc.value * HALF_EL;
        gload(s, d); gload(s + (size_t)8 * N_TOT, d + 512);
    };
    auto stB = [&](auto SlC, auto Hc, auto Dc) {
        const u16* s = bT + (size_t)(Hc.value * 128) * N_TOT + Dc.value;
        u16* d = sdB + SlC.value * SLOT_EL + Hc.value * HALF_EL;
        gload(s, d); gload(s + (size_t)8 * N_TOT, d + 512);
    };

    // fragment read bases: [slot][ks], all ds_read offsets are sub-32KB imms
    const int cc0 = (((lane >> 4) << 3)) ^ ((lane & 7) << 3);
    const int rA  = ((wm << 4) + (lane & 15)) << 6;
    const int rB  = ((wn << 4) + (lane & 15)) << 6;
    const u16* pAk[2][2];
    const u16* pBk[2][2];
    pAk[0][0] = &lds[rA + cc0];
    pAk[0][1] = &lds[rA + (cc0 ^ 32)];
    pAk[1][0] = pAk[0][0] + SLOT_EL;
    pAk[1][1] = pAk[0][1] + SLOT_EL;
    pBk[0][0] = &lds[B_OFF + rB + cc0];
    pBk[0][1] = &lds[B_OFF + rB + (cc0 ^ 32)];
    pBk[1][0] = pBk[0][0] + SLOT_EL;
    pBk[1][1] = pBk[0][1] + SLOT_EL;

    f32x4 acc[2][2][4][2] = {};
    bf16x8 af[2][4][2];   // [mh][j][ks]
    bf16x8 bfr[2][2][2];  // [nh][j2][ks]

    // read-ahead: quadrant (0,0)'s fragments (A0 8 + B0 4) from slot SL
    auto readP0 = [&](auto SlC) {
        constexpr int SL = SlC.value;
        #pragma unroll
        for (int j = 0; j < 4; ++j) {
            af[0][j][0] = *(const bf16x8*)(pAk[SL][0] + j * 2048);
            af[0][j][1] = *(const bf16x8*)(pAk[SL][1] + j * 2048);
        }
        #pragma unroll
        for (int j2 = 0; j2 < 2; ++j2) {
            bfr[0][j2][0] = *(const bf16x8*)(pBk[SL][0] + j2 * 4096);
            bfr[0][j2][1] = *(const bf16x8*)(pBk[SL][1] + j2 * 4096);
        }
    };

    // one K-tile, slot SL; optionally stage t+1 (source delta D) and read-ahead
    auto tile = [&](auto SlC, auto StC, auto Dc, auto AhC) {
        constexpr int SL = SlC.value;
        constexpr bool ST = StC.value;
        constexpr bool AH = AhC.value;

        // stage ALL of t+1 into slot^1 at tile top (max flight distance)
        if constexpr (ST) {
            stA(ic<SL ^ 1>{}, ic<0>{}, Dc);
            stB(ic<SL ^ 1>{}, ic<0>{}, Dc);
            stA(ic<SL ^ 1>{}, ic<1>{}, Dc);
            stB(ic<SL ^ 1>{}, ic<1>{}, Dc);
        }
        // in-tile reads: B1 (p1) then A1 (p2)
        #pragma unroll
        for (int j2 = 0; j2 < 2; ++j2) {
            bfr[1][j2][0] = *(const bf16x8*)(pBk[SL][0] + HALF_EL + j2 * 4096);
            bfr[1][j2][1] = *(const bf16x8*)(pBk[SL][1] + HALF_EL + j2 * 4096);
        }
        #pragma unroll
        for (int j = 0; j < 4; ++j) {
            af[1][j][0] = *(const bf16x8*)(pAk[SL][0] + HALF_EL + j * 2048);
            af[1][j][1] = *(const bf16x8*)(pAk[SL][1] + HALF_EL + j * 2048);
        }

        __builtin_amdgcn_s_setprio(1);
        // gray-code quadrants: (0,0) (0,1) (1,1) (1,0); compiler inserts
        // counted lgkm waits per cluster -> LDS pipe never drains.
        #pragma unroll
        for (int ks = 0; ks < 2; ++ks)
            #pragma unroll
            for (int j = 0; j < 4; ++j)
                #pragma unroll
                for (int j2 = 0; j2 < 2; ++j2)
                    acc[0][0][j][j2] = __builtin_amdgcn_mfma_f32_16x16x32_bf16(
                        af[0][j][ks], bfr[0][j2][ks], acc[0][0][j][j2], 0, 0, 0);
        #pragma unroll
        for (int ks = 0; ks < 2; ++ks)
            #pragma unroll
            for (int j = 0; j < 4; ++j)
                #pragma unroll
                for (int j2 = 0; j2 < 2; ++j2)
                    acc[0][1][j][j2] = __builtin_amdgcn_mfma_f32_16x16x32_bf16(
                        af[0][j][ks], bfr[1][j2][ks], acc[0][1][j][j2], 0, 0, 0);
        #pragma unroll
        for (int ks = 0; ks < 2; ++ks)
            #pragma unroll
            for (int j = 0; j < 4; ++j)
                #pragma unroll
                for (int j2 = 0; j2 < 2; ++j2)
                    acc[1][1][j][j2] = __builtin_amdgcn_mfma_f32_16x16x32_bf16(
                        af[1][j][ks], bfr[1][j2][ks], acc[1][1][j][j2], 0, 0, 0);
        #pragma unroll
        for (int ks = 0; ks < 2; ++ks)
            #pragma unroll
            for (int j = 0; j < 4; ++j)
                #pragma unroll
                for (int j2 = 0; j2 < 2; ++j2)
                    acc[1][0][j][j2] = __builtin_amdgcn_mfma_f32_16x16x32_bf16(
                        af[1][j][ks], bfr[0][j2][ks], acc[1][0][j][j2], 0, 0, 0);
        __builtin_amdgcn_s_setprio(0);

        if constexpr (ST || AH) {
            asm volatile("s_waitcnt vmcnt(0)" ::: "memory");  // drains old stages
            __builtin_amdgcn_s_barrier();
        }
        if constexpr (AH) readP0(ic<SL ^ 1>{});   // cross-barrier read-ahead
    };

    // prologue: stage tile 0 -> slot 0; then first read-ahead
    stA(ic<0>{}, ic<0>{}, ic<0>{});
    stB(ic<0>{}, ic<0>{}, ic<0>{});
    stA(ic<0>{}, ic<1>{}, ic<0>{});
    stB(ic<0>{}, ic<1>{}, ic<0>{});
    asm volatile("s_waitcnt vmcnt(0)" ::: "memory");
    __builtin_amdgcn_s_barrier();
    readP0(ic<0>{});

    // steady: tiles 0..61 as 31 slot pairs; aT/bT advance 2*BK per pair.
    // stage deltas: SL0 tile stages t+1 at +BK; SL1 tile at +2*BK.
    for (int it = 0; it < 31; ++it) {
        tile(ic<0>{}, bc<true>{}, ic<BK>{},     bc<true>{});
        tile(ic<1>{}, bc<true>{}, ic<2 * BK>{}, bc<true>{});
        aT += 2 * BK;
        bT += 2 * BK;
    }
    // tile 62 (slot 0): stage tile 63 (+BK), read-ahead its p0
    tile(ic<0>{}, bc<true>{}, ic<BK>{}, bc<true>{});
    // tile 63 (slot 1): nothing follows
    tile(ic<1>{}, bc<false>{}, ic<0>{}, bc<false>{});

    // epilogue: C/D layout col = lane&15 (out-dim), row = (lane>>4)*4 + rr (M)
    #pragma unroll
    for (int mh_ = 0; mh_ < 2; ++mh_)
        #pragma unroll
        for (int j = 0; j < 4; ++j)
            #pragma unroll
            for (int rr = 0; rr < 4; ++rr) {
                const int row = bm * BM + mh_ * 128 + j * 32 + wm * 16 + ((lane >> 4) << 2) + rr;
                float* orow = out + (size_t)row * K_TOT;
                #pragma unroll
                for (int nh_ = 0; nh_ < 2; ++nh_)
                    #pragma unroll
                    for (int j2 = 0; j2 < 2; ++j2) {
                        const int col = bn * BN + nh_ * 128 + j2 * 64 + wn * 16 + (lane & 15);
                        orow[col] = acc[mh_][nh_][j][j2][rr] + bias[col];
                    }
            }
}

extern "C" void kernel_launch(void* const* d_in, const int* in_sizes, int n_in,
                              void* d_out, int out_size, void* d_ws, size_t ws_size,
                              hipStream_t stream) {
    const float* x      = (const float*)d_in[0];
    const float* scales = (const float*)d_in[1];
    const float* zeros  = (const float*)d_in[2];
    const float* mu1    = (const float*)d_in[3];
    const float* mu2    = (const float*)d_in[4];
    const float* bias   = (const float*)d_in[5];
    const int*   wq     = (const int*)d_in[6];
    float* out = (float*)d_out;

    u16* xb = (u16*)d_ws;                                 // 64 MiB
    u16* wb = (u16*)d_ws + (size_t)M_TOT * N_TOT;         // 32 MiB

    cvt_x_kernel<<<(M_TOT * N_TOT / 8) / 256, 256, 0, stream>>>(x, xb);
    deq_w_kernel<<<(K_TOT * N_TOT / 8) / 256, 256, 0, stream>>>(wq, scales, zeros, mu1, mu2, wb);
    gemm_kernel<<<(M_TOT / BM) * (K_TOT / BN), 512, 0, stream>>>(xb, wb, bias, out);
}

// Round 9
// 2994.017 us; speedup vs baseline: 1.2300x; 1.2300x over previous
//
#include <hip/hip_runtime.h>
#include <hip/hip_bf16.h>
#include <stdint.h>
#include <type_traits>

typedef unsigned short u16;
typedef __bf16 bf16x8 __attribute__((ext_vector_type(8)));
typedef float f32x4 __attribute__((ext_vector_type(4)));

#define M_TOT 8192   // B*S
#define N_TOT 4096   // reduction dim
#define K_TOT 4096   // output dim
#define BM 256
#define BN 256
#define BK 64
#define NT 64        // N_TOT / BK

// LDS geometry in u16 elements: [slot][A:2 halves | B:2 halves][128][64]
#define HALF_EL 8192     // 128 rows * 64 cols
#define B_OFF   16384
#define SLOT_EL 32768    // 64 KiB per slot

template <int V> using ic = std::integral_constant<int, V>;
template <bool V> using bc = std::integral_constant<bool, V>;

__device__ __forceinline__ u16 f2bf(float f) {
    union { float f; uint32_t u; } v; v.f = f;
    uint32_t u = v.u;
    return (u16)((u + 0x7fffu + ((u >> 16) & 1u)) >> 16);
}

// ---- pre-pass 1: x fp32 -> bf16 ----------------------------------------------
__global__ __launch_bounds__(256) void cvt_x_kernel(const float* __restrict__ x,
                                                    u16* __restrict__ xb) {
    const int i = blockIdx.x * blockDim.x + threadIdx.x;
    const float4* p = (const float4*)x + (size_t)i * 2;
    float4 v0 = p[0], v1 = p[1];
    uint4 o;
    o.x = (uint32_t)f2bf(v0.x) | ((uint32_t)f2bf(v0.y) << 16);
    o.y = (uint32_t)f2bf(v0.z) | ((uint32_t)f2bf(v0.w) << 16);
    o.z = (uint32_t)f2bf(v1.x) | ((uint32_t)f2bf(v1.y) << 16);
    o.w = (uint32_t)f2bf(v1.z) | ((uint32_t)f2bf(v1.w) << 16);
    *((uint4*)(xb + (size_t)i * 8)) = o;
}

// ---- pre-pass 2: dequantize W_q -> bf16 --------------------------------------
__global__ __launch_bounds__(256) void deq_w_kernel(const int* __restrict__ wq,
                                                    const float* __restrict__ scales,
                                                    const float* __restrict__ zeros,
                                                    const float* __restrict__ mu1,
                                                    const float* __restrict__ mu2,
                                                    u16* __restrict__ wb) {
    const int i = blockIdx.x * blockDim.x + threadIdx.x;
    const int k  = i >> 9;
    const int n0 = (i & 511) << 3;
    const int g  = n0 >> 6;
    const float z  = zeros[k * 64 + g];
    const float sm = scales[k * 64 + g] * mu2[k];
    const int4* qp = (const int4*)(wq + (size_t)k * N_TOT + n0);
    int4 q0 = qp[0], q1 = qp[1];
    const float4* mp = (const float4*)(mu1 + n0);
    float4 u0 = mp[0], u1 = mp[1];
    uint4 o;
    o.x = (uint32_t)f2bf(((float)q0.x - z) * sm * u0.x) |
          ((uint32_t)f2bf(((float)q0.y - z) * sm * u0.y) << 16);
    o.y = (uint32_t)f2bf(((float)q0.z - z) * sm * u0.z) |
          ((uint32_t)f2bf(((float)q0.w - z) * sm * u0.w) << 16);
    o.z = (uint32_t)f2bf(((float)q1.x - z) * sm * u1.x) |
          ((uint32_t)f2bf(((float)q1.y - z) * sm * u1.y) << 16);
    o.w = (uint32_t)f2bf(((float)q1.z - z) * sm * u1.z) |
          ((uint32_t)f2bf(((float)q1.w - z) * sm * u1.w) << 16);
    *((uint4*)(wb + (size_t)k * N_TOT + n0)) = o;
}

// ---- main GEMM: continuous-flow, register-budgeted -----------------------------
// 8 waves (2M x 4N), per-wave out 128x64, BK=64, double-buffered LDS.
// Per K-tile t (slot S=t&1), 1 barrier, NO explicit lgkm waits:
//   stage t+1 -> S^1 (8 gloads, full-tile vmcnt distance)
//   read bf1(S); MFMA q0(afLo,bf0)          <- q0 frags prefetched last tile
//   read afHi(S); MFMA q1(afLo,bf1)
//   MFMA q2(afHi,bf1); MFMA q3(afHi,bf0)
//   vmcnt(0) [drains this tile's stages, ~2500cyc old]; s_barrier
//   prefetch next q0: afLo,bf0 <- S^1
// Compiler emits counted lgkm waits per consumer -> LDS services next
// quadrant's reads UNDER the current MFMA cluster; waves desync within tile.
// Fragment liveness: max concurrent = afLo+afHi+bf0+bf1 = 96 VGPR (R4-proven);
// prefetch overwrites only dead regs (afLo dead after q1, bf0 after q3).
// Liveness/race proof: tile t reads only S; all waves' S^1-reads complete
// before their own pre-barrier MFMA consumers (counted lgkm), so post-barrier
// staging to S^1 is safe; prefetch reads S^1 only after vmcnt(0)+barrier.
// LDS XOR swizzle (proven R2): physical col = logical ^ ((row&7)*8 elems);
// linear gload_lds dest + inverse-swizzled global source + swizzled ds_read.
__global__ __launch_bounds__(512, 2) void gemm_kernel(const u16* __restrict__ Xb,
                                                      const u16* __restrict__ Wb,
                                                      const float* __restrict__ bias,
                                                      float* __restrict__ out) {
    __shared__ __align__(16) u16 lds[2 * SLOT_EL];   // 128 KiB

    // XCD-bijective swizzle: nwg = 512, divisible by 8
    const int bid = blockIdx.x;
    const int cpx = gridDim.x >> 3;
    const int swz = (bid & 7) * cpx + (bid >> 3);
    const int bm = swz >> 4;    // 32 M-tiles
    const int bn = swz & 15;    // 16 out-tiles

    const int tid  = threadIdx.x;
    const int w    = tid >> 6;
    const int lane = tid & 63;
    const int wm = w >> 2, wn = w & 3;

    // staging: lane l, issue i covers LDS row (w*16 + i*8 + (l>>3)), physical
    // col (l&7)*16B; global col pre-swizzled: ((l&7)^(l>>3))*8 elems.
    const int scol = (((lane & 7) ^ (lane >> 3)) << 3);
    const u16* aT = Xb + (size_t)(bm * BM + w * 16 + (lane >> 3)) * N_TOT + scol;
    const u16* bT = Wb + (size_t)(bn * BN + w * 16 + (lane >> 3)) * N_TOT + scol;

    u16* const sdA = &lds[w * 1024];
    u16* const sdB = &lds[B_OFF + w * 1024];

    auto gload = [](const u16* s, u16* d) {
        __builtin_amdgcn_global_load_lds(
            (const __attribute__((address_space(1))) uint32_t*)s,
            (__attribute__((address_space(3))) uint32_t*)d, 16, 0, 0);
    };
    auto stA = [&](auto SlC, auto Hc, auto Dc) {
        const u16* s = aT + (size_t)(Hc.value * 128) * N_TOT + Dc.value;
        u16* d = sdA + SlC.value * SLOT_EL + Hc.value * HALF_EL;
        gload(s, d); gload(s + (size_t)8 * N_TOT, d + 512);
    };
    auto stB = [&](auto SlC, auto Hc, auto Dc) {
        const u16* s = bT + (size_t)(Hc.value * 128) * N_TOT + Dc.value;
        u16* d = sdB + SlC.value * SLOT_EL + Hc.value * HALF_EL;
        gload(s, d); gload(s + (size_t)8 * N_TOT, d + 512);
    };

    // fragment read bases: [slot][ks]; all in-slot ds_read offsets are <64KB imms
    const int cc0 = (((lane >> 4) << 3)) ^ ((lane & 7) << 3);
    const int rA  = ((wm << 4) + (lane & 15)) << 6;
    const int rB  = ((wn << 4) + (lane & 15)) << 6;
    const u16* pAk[2][2];
    const u16* pBk[2][2];
    pAk[0][0] = &lds[rA + cc0];
    pAk[0][1] = &lds[rA + (cc0 ^ 32)];
    pAk[1][0] = pAk[0][0] + SLOT_EL;
    pAk[1][1] = pAk[0][1] + SLOT_EL;
    pBk[0][0] = &lds[B_OFF + rB + cc0];
    pBk[0][1] = &lds[B_OFF + rB + (cc0 ^ 32)];
    pBk[1][0] = pBk[0][0] + SLOT_EL;
    pBk[1][1] = pBk[0][1] + SLOT_EL;

    f32x4 acc[2][2][4][2] = {};
    bf16x8 afLo[4][2], afHi[4][2];   // [j][ks]  (A half0 / half1)
    bf16x8 bf0[2][2], bf1[2][2];     // [j2][ks] (B half0 / half1)

    // prefetch quadrant-0 fragments (A half0 + B half0) from slot SL
    auto readQ0 = [&](auto SlC) {
        constexpr int SL = SlC.value;
        #pragma unroll
        for (int j = 0; j < 4; ++j) {
            afLo[j][0] = *(const bf16x8*)(pAk[SL][0] + j * 2048);
            afLo[j][1] = *(const bf16x8*)(pAk[SL][1] + j * 2048);
        }
        #pragma unroll
        for (int j2 = 0; j2 < 2; ++j2) {
            bf0[j2][0] = *(const bf16x8*)(pBk[SL][0] + j2 * 4096);
            bf0[j2][1] = *(const bf16x8*)(pBk[SL][1] + j2 * 4096);
        }
    };

    #define MFMA_CLUSTER(A, B, MH, NH)                                          \
        __builtin_amdgcn_s_setprio(1);                                          \
        _Pragma("unroll")                                                       \
        for (int ks = 0; ks < 2; ++ks)                                          \
            _Pragma("unroll")                                                   \
            for (int j = 0; j < 4; ++j)                                         \
                _Pragma("unroll")                                               \
                for (int j2 = 0; j2 < 2; ++j2)                                  \
                    acc[MH][NH][j][j2] = __builtin_amdgcn_mfma_f32_16x16x32_bf16(\
                        A[j][ks], B[j2][ks], acc[MH][NH][j][j2], 0, 0, 0);      \
        __builtin_amdgcn_s_setprio(0);

    // one K-tile; SL = slot, ST = stage next tile (source delta D), LAST = tail
    auto tile = [&](auto SlC, auto StC, auto Dc, auto LastC) {
        constexpr int SL = SlC.value;
        constexpr bool ST = StC.value;
        constexpr bool LAST = LastC.value;

        if constexpr (ST) {
            stA(ic<SL ^ 1>{}, ic<0>{}, Dc);
            stB(ic<SL ^ 1>{}, ic<0>{}, Dc);
            stA(ic<SL ^ 1>{}, ic<1>{}, Dc);
            stB(ic<SL ^ 1>{}, ic<1>{}, Dc);
        }
        // read B half1 (q1/q2 operand)
        #pragma unroll
        for (int j2 = 0; j2 < 2; ++j2) {
            bf1[j2][0] = *(const bf16x8*)(pBk[SL][0] + HALF_EL + j2 * 4096);
            bf1[j2][1] = *(const bf16x8*)(pBk[SL][1] + HALF_EL + j2 * 4096);
        }
        MFMA_CLUSTER(afLo, bf0, 0, 0)            // q0
        // read A half1 (q2/q3 operand)
        #pragma unroll
        for (int j = 0; j < 4; ++j) {
            afHi[j][0] = *(const bf16x8*)(pAk[SL][0] + HALF_EL + j * 2048);
            afHi[j][1] = *(const bf16x8*)(pAk[SL][1] + HALF_EL + j * 2048);
        }
        MFMA_CLUSTER(afLo, bf1, 0, 1)            // q1   (afLo dead after)
        MFMA_CLUSTER(afHi, bf1, 1, 1)            // q2   (bf1 dead after)
        MFMA_CLUSTER(afHi, bf0, 1, 0)            // q3   (afHi, bf0 dead after)

        if constexpr (!LAST) {
            asm volatile("s_waitcnt vmcnt(0)" ::: "memory");  // stages ~1 tile old
            __builtin_amdgcn_s_barrier();
            readQ0(ic<SL ^ 1>{});                // prefetch next tile's q0
        }
    };

    // prologue: stage tile 0 -> slot 0; first q0 prefetch
    stA(ic<0>{}, ic<0>{}, ic<0>{});
    stB(ic<0>{}, ic<0>{}, ic<0>{});
    stA(ic<0>{}, ic<1>{}, ic<0>{});
    stB(ic<0>{}, ic<1>{}, ic<0>{});
    asm volatile("s_waitcnt vmcnt(0)" ::: "memory");
    __builtin_amdgcn_s_barrier();
    readQ0(ic<0>{});

    // steady: tiles 0..61 as 31 slot pairs; aT/bT advance 2*BK per pair
    for (int it = 0; it < 31; ++it) {
        tile(ic<0>{}, bc<true>{}, ic<BK>{},     bc<false>{});
        tile(ic<1>{}, bc<true>{}, ic<2 * BK>{}, bc<false>{});
        aT += 2 * BK;
        bT += 2 * BK;
    }
    // tile 62 (slot 0): stage tile 63; prefetch its q0
    tile(ic<0>{}, bc<true>{}, ic<BK>{}, bc<false>{});
    // tile 63 (slot 1): tail — no stage, no trailing sync
    tile(ic<1>{}, bc<false>{}, ic<0>{}, bc<true>{});

    #undef MFMA_CLUSTER

    // epilogue: C/D layout col = lane&15 (out-dim), row = (lane>>4)*4 + rr (M)
    #pragma unroll
    for (int mh_ = 0; mh_ < 2; ++mh_)
        #pragma unroll
        for (int j = 0; j < 4; ++j)
            #pragma unroll
            for (int rr = 0; rr < 4; ++rr) {
                const int row = bm * BM + mh_ * 128 + j * 32 + wm * 16 + ((lane >> 4) << 2) + rr;
                float* orow = out + (size_t)row * K_TOT;
                #pragma unroll
                for (int nh_ = 0; nh_ < 2; ++nh_)
                    #pragma unroll
                    for (int j2 = 0; j2 < 2; ++j2) {
                        const int col = bn * BN + nh_ * 128 + j2 * 64 + wn * 16 + (lane & 15);
                        orow[col] = acc[mh_][nh_][j][j2][rr] + bias[col];
                    }
            }
}

extern "C" void kernel_launch(void* const* d_in, const int* in_sizes, int n_in,
                              void* d_out, int out_size, void* d_ws, size_t ws_size,
                              hipStream_t stream) {
    const float* x      = (const float*)d_in[0];
    const float* scales = (const float*)d_in[1];
    const float* zeros  = (const float*)d_in[2];
    const float* mu1    = (const float*)d_in[3];
    const float* mu2    = (const float*)d_in[4];
    const float* bias   = (const float*)d_in[5];
    const int*   wq     = (const int*)d_in[6];
    float* out = (float*)d_out;

    u16* xb = (u16*)d_ws;                                 // 64 MiB
    u16* wb = (u16*)d_ws + (size_t)M_TOT * N_TOT;         // 32 MiB

    cvt_x_kernel<<<(M_TOT * N_TOT / 8) / 256, 256, 0, stream>>>(x, xb);
    deq_w_kernel<<<(K_TOT * N_TOT / 8) / 256, 256, 0, stream>>>(wq, scales, zeros, mu1, mu2, wb);
    gemm_kernel<<<(M_TOT / BM) * (K_TOT / BN), 512, 0, stream>>>(xb, wb, bias, out);
}

// Round 10
// 291.444 us; speedup vs baseline: 12.6357x; 10.2731x over previous
//
#include <hip/hip_runtime.h>
#include <hip/hip_bf16.h>
#include <stdint.h>
#include <type_traits>

typedef unsigned short u16;
typedef __bf16 bf16x8 __attribute__((ext_vector_type(8)));
typedef float f32x4 __attribute__((ext_vector_type(4)));

#define M_TOT 8192   // B*S
#define N_TOT 4096   // reduction dim
#define K_TOT 4096   // output dim
#define BM 256
#define BN 256
#define BK 64
#define NT 64        // N_TOT / BK

// LDS geometry in u16 elements: [slot][A:2 halves | B:2 halves][128][64]
#define HALF_EL 8192     // 128 rows * 64 cols
#define B_OFF   16384
#define SLOT_EL 32768    // 64 KiB per slot

template <int V> using ic = std::integral_constant<int, V>;
template <bool V> using bc = std::integral_constant<bool, V>;

__device__ __forceinline__ u16 f2bf(float f) {
    union { float f; uint32_t u; } v; v.f = f;
    uint32_t u = v.u;
    return (u16)((u + 0x7fffu + ((u >> 16) & 1u)) >> 16);
}

// ---- pre-pass 1: x fp32 -> bf16 ----------------------------------------------
__global__ __launch_bounds__(256) void cvt_x_kernel(const float* __restrict__ x,
                                                    u16* __restrict__ xb) {
    const int i = blockIdx.x * blockDim.x + threadIdx.x;
    const float4* p = (const float4*)x + (size_t)i * 2;
    float4 v0 = p[0], v1 = p[1];
    uint4 o;
    o.x = (uint32_t)f2bf(v0.x) | ((uint32_t)f2bf(v0.y) << 16);
    o.y = (uint32_t)f2bf(v0.z) | ((uint32_t)f2bf(v0.w) << 16);
    o.z = (uint32_t)f2bf(v1.x) | ((uint32_t)f2bf(v1.y) << 16);
    o.w = (uint32_t)f2bf(v1.z) | ((uint32_t)f2bf(v1.w) << 16);
    *((uint4*)(xb + (size_t)i * 8)) = o;
}

// ---- pre-pass 2: dequantize W_q -> bf16 --------------------------------------
__global__ __launch_bounds__(256) void deq_w_kernel(const int* __restrict__ wq,
                                                    const float* __restrict__ scales,
                                                    const float* __restrict__ zeros,
                                                    const float* __restrict__ mu1,
                                                    const float* __restrict__ mu2,
                                                    u16* __restrict__ wb) {
    const int i = blockIdx.x * blockDim.x + threadIdx.x;
    const int k  = i >> 9;
    const int n0 = (i & 511) << 3;
    const int g  = n0 >> 6;
    const float z  = zeros[k * 64 + g];
    const float sm = scales[k * 64 + g] * mu2[k];
    const int4* qp = (const int4*)(wq + (size_t)k * N_TOT + n0);
    int4 q0 = qp[0], q1 = qp[1];
    const float4* mp = (const float4*)(mu1 + n0);
    float4 u0 = mp[0], u1 = mp[1];
    uint4 o;
    o.x = (uint32_t)f2bf(((float)q0.x - z) * sm * u0.x) |
          ((uint32_t)f2bf(((float)q0.y - z) * sm * u0.y) << 16);
    o.y = (uint32_t)f2bf(((float)q0.z - z) * sm * u0.z) |
          ((uint32_t)f2bf(((float)q0.w - z) * sm * u0.w) << 16);
    o.z = (uint32_t)f2bf(((float)q1.x - z) * sm * u1.x) |
          ((uint32_t)f2bf(((float)q1.y - z) * sm * u1.y) << 16);
    o.w = (uint32_t)f2bf(((float)q1.z - z) * sm * u1.z) |
          ((uint32_t)f2bf(((float)q1.w - z) * sm * u1.w) << 16);
    *((uint4*)(wb + (size_t)k * N_TOT + n0)) = o;
}

// ---- main GEMM: 256x256 8-phase with ONE-AHEAD fragment pipeline --------------
// 8 waves (2M x 4N), per-wave out 128x64, BK=64, double-buffered LDS.
// Quadrants: p0=(A0,B0) p1=(A0,B1) p2=(A1,B1) p3=(A1,B0).
// Register groups afLo(A0,8xb128) afHi(A1,8) bf0(B0,4) bf1(B1,4) = 96 VGPR cap.
// ONE-AHEAD reads (each overwrites a dead group; consumed >=1 full MFMA
// cluster after issue -> LDS latency hides under MFMA; NO explicit lgkm,
// compiler emits counted waits at consumers):
//   p0-top: bf1[SL]      (dead since prev p2; used p1)
//   p1-top: afHi[SL]     (dead since prev p3; used p2)
//   p2-top: afLo[SL^1]   (dead since p1;     used next p0)  <- next tile
//   p3 post-MFMA: bf0[SL^1] (dead after p3 MFMA; used next p0)
// Stages (2 gloads per half-tile per thread):
//   p0: A1,B1(t+1)->SL^1   p1: A0,B0(t+2)->SL
// Counted vmcnt: p1: vmcnt(8) [outstanding t-1.p1(4)+t.p0(4)+t.p1(4)=12 ->
// drains t-1.p1 = A0,B0(t+1), needed by p2/p3 reads]; p3: vmcnt(4)
// [t.p0(4)+t.p1(4)=8 -> drains t.p0 = A1,B1(t+1), needed by t+1.p0/p1 reads].
// Stage->read separation >= 3 phases (~2400cyc > 900 HBM latency).
// WAR safety: every ds_read is lgkm-complete before its phase's closing
// barrier (its consumer MFMA sits in between); conflicting stage-writes
// issue >=1 barrier later. 2 barriers/phase (m201 discipline).
// LDS XOR swizzle (proven R2): physical col = logical ^ ((row&7)*8 elems).
__global__ __launch_bounds__(512, 2) void gemm_kernel(const u16* __restrict__ Xb,
                                                      const u16* __restrict__ Wb,
                                                      const float* __restrict__ bias,
                                                      float* __restrict__ out) {
    __shared__ __align__(16) u16 lds[2 * SLOT_EL];   // 128 KiB

    // XCD-bijective swizzle: nwg = 512, divisible by 8
    const int bid = blockIdx.x;
    const int cpx = gridDim.x >> 3;
    const int swz = (bid & 7) * cpx + (bid >> 3);
    const int bm = swz >> 4;    // 32 M-tiles
    const int bn = swz & 15;    // 16 out-tiles

    const int tid  = threadIdx.x;
    const int w    = tid >> 6;
    const int lane = tid & 63;
    const int wm = w >> 2, wn = w & 3;

    // staging: lane l, issue i covers LDS row (w*16 + i*8 + (l>>3)), physical
    // col (l&7)*16B; global col pre-swizzled: ((l&7)^(l>>3))*8 elems.
    const int scol = (((lane & 7) ^ (lane >> 3)) << 3);
    const u16* aT = Xb + (size_t)(bm * BM + w * 16 + (lane >> 3)) * N_TOT + scol;
    const u16* bT = Wb + (size_t)(bn * BN + w * 16 + (lane >> 3)) * N_TOT + scol;

    u16* const sdA = &lds[w * 1024];
    u16* const sdB = &lds[B_OFF + w * 1024];

    auto gload = [](const u16* s, u16* d) {
        __builtin_amdgcn_global_load_lds(
            (const __attribute__((address_space(1))) uint32_t*)s,
            (__attribute__((address_space(3))) uint32_t*)d, 16, 0, 0);
    };
    auto stA = [&](auto SlC, auto Hc, auto Dc) {
        const u16* s = aT + (size_t)(Hc.value * 128) * N_TOT + Dc.value;
        u16* d = sdA + SlC.value * SLOT_EL + Hc.value * HALF_EL;
        gload(s, d); gload(s + (size_t)8 * N_TOT, d + 512);
    };
    auto stB = [&](auto SlC, auto Hc, auto Dc) {
        const u16* s = bT + (size_t)(Hc.value * 128) * N_TOT + Dc.value;
        u16* d = sdB + SlC.value * SLOT_EL + Hc.value * HALF_EL;
        gload(s, d); gload(s + (size_t)8 * N_TOT, d + 512);
    };

    // fragment read bases: [slot][ks]; in-slot ds_read offsets are imm
    const int cc0 = (((lane >> 4) << 3)) ^ ((lane & 7) << 3);
    const int rA  = ((wm << 4) + (lane & 15)) << 6;
    const int rB  = ((wn << 4) + (lane & 15)) << 6;
    const u16* pAk[2][2];
    const u16* pBk[2][2];
    pAk[0][0] = &lds[rA + cc0];
    pAk[0][1] = &lds[rA + (cc0 ^ 32)];
    pAk[1][0] = pAk[0][0] + SLOT_EL;
    pAk[1][1] = pAk[0][1] + SLOT_EL;
    pBk[0][0] = &lds[B_OFF + rB + cc0];
    pBk[0][1] = &lds[B_OFF + rB + (cc0 ^ 32)];
    pBk[1][0] = pBk[0][0] + SLOT_EL;
    pBk[1][1] = pBk[0][1] + SLOT_EL;

    f32x4 acc[2][2][4][2] = {};
    bf16x8 afLo[4][2], afHi[4][2];   // [j][ks]
    bf16x8 bf0[2][2], bf1[2][2];     // [j2][ks]

    auto rd_afLo = [&](auto SlC) {
        constexpr int SL = SlC.value;
        #pragma unroll
        for (int j = 0; j < 4; ++j) {
            afLo[j][0] = *(const bf16x8*)(pAk[SL][0] + j * 2048);
            afLo[j][1] = *(const bf16x8*)(pAk[SL][1] + j * 2048);
        }
    };
    auto rd_afHi = [&](auto SlC) {
        constexpr int SL = SlC.value;
        #pragma unroll
        for (int j = 0; j < 4; ++j) {
            afHi[j][0] = *(const bf16x8*)(pAk[SL][0] + HALF_EL + j * 2048);
            afHi[j][1] = *(const bf16x8*)(pAk[SL][1] + HALF_EL + j * 2048);
        }
    };
    auto rd_bf0 = [&](auto SlC) {
        constexpr int SL = SlC.value;
        #pragma unroll
        for (int j2 = 0; j2 < 2; ++j2) {
            bf0[j2][0] = *(const bf16x8*)(pBk[SL][0] + j2 * 4096);
            bf0[j2][1] = *(const bf16x8*)(pBk[SL][1] + j2 * 4096);
        }
    };
    auto rd_bf1 = [&](auto SlC) {
        constexpr int SL = SlC.value;
        #pragma unroll
        for (int j2 = 0; j2 < 2; ++j2) {
            bf1[j2][0] = *(const bf16x8*)(pBk[SL][0] + HALF_EL + j2 * 4096);
            bf1[j2][1] = *(const bf16x8*)(pBk[SL][1] + HALF_EL + j2 * 4096);
        }
    };

    auto vmw = [](auto Vc) {
        constexpr int V = Vc.value;
        if constexpr (V == 8)      asm volatile("s_waitcnt vmcnt(8)" ::: "memory");
        else if constexpr (V == 4) asm volatile("s_waitcnt vmcnt(4)" ::: "memory");
        else if constexpr (V == 0) asm volatile("s_waitcnt vmcnt(0)" ::: "memory");
    };

    #define MFMA_CLUSTER(A, B, MH, NH)                                          \
        __builtin_amdgcn_s_setprio(1);                                          \
        _Pragma("unroll")                                                       \
        for (int ks = 0; ks < 2; ++ks)                                          \
            _Pragma("unroll")                                                   \
            for (int j = 0; j < 4; ++j)                                         \
                _Pragma("unroll")                                               \
                for (int j2 = 0; j2 < 2; ++j2)                                  \
                    acc[MH][NH][j][j2] = __builtin_amdgcn_mfma_f32_16x16x32_bf16(\
                        A[j][ks], B[j2][ks], acc[MH][NH][j][j2], 0, 0, 0);      \
        __builtin_amdgcn_s_setprio(0);

    // one K-tile: SL slot; St0/St1 stage enables; Rd23 cross-tile reads;
    // Vm1/Vm3 counted vmcnt values; D0/D1 global source deltas.
    auto ktile = [&](auto SlC, auto St0, auto St1, auto Rd23,
                     auto Vm1, auto Vm3, auto D0, auto D1) {
        constexpr int SL = SlC.value;
        // ---- p0: quadrant (A0,B0) ----
        rd_bf1(SlC);
        if constexpr (St0.value) { stA(ic<SL ^ 1>{}, ic<1>{}, D0);
                                   stB(ic<SL ^ 1>{}, ic<1>{}, D0); }
        __builtin_amdgcn_s_barrier();
        MFMA_CLUSTER(afLo, bf0, 0, 0)
        __builtin_amdgcn_s_barrier();
        // ---- p1: quadrant (A0,B1) ----
        rd_afHi(SlC);
        if constexpr (St1.value) { stA(SlC, ic<0>{}, D1);
                                   stB(SlC, ic<0>{}, D1); }
        __builtin_amdgcn_s_barrier();
        MFMA_CLUSTER(afLo, bf1, 0, 1)
        vmw(Vm1);
        __builtin_amdgcn_s_barrier();
        // ---- p2: quadrant (A1,B1) ----
        if constexpr (Rd23.value) rd_afLo(ic<SL ^ 1>{});
        __builtin_amdgcn_s_barrier();
        MFMA_CLUSTER(afHi, bf1, 1, 1)
        __builtin_amdgcn_s_barrier();
        // ---- p3: quadrant (A1,B0) ----
        MFMA_CLUSTER(afHi, bf0, 1, 0)
        if constexpr (Rd23.value) rd_bf0(ic<SL ^ 1>{});
        vmw(Vm3);
        __builtin_amdgcn_s_barrier();
    };

    // prologue: stage tile0 (8) + A0,B0(tile1) (4) -> vmcnt(4) drains tile0,
    // leaves A0,B0(1) in flight (the steady-state "t-1.p1" residue).
    stA(ic<0>{}, ic<0>{}, ic<0>{});  stB(ic<0>{}, ic<0>{}, ic<0>{});
    stA(ic<0>{}, ic<1>{}, ic<0>{});  stB(ic<0>{}, ic<1>{}, ic<0>{});
    stA(ic<1>{}, ic<0>{}, ic<BK>{}); stB(ic<1>{}, ic<0>{}, ic<BK>{});
    asm volatile("s_waitcnt vmcnt(4)" ::: "memory");
    __builtin_amdgcn_s_barrier();
    rd_afLo(ic<0>{});
    rd_bf0(ic<0>{});

    // steady: 31 pairs = tiles 0..61 (aT/bT at even tile of pair)
    for (int it = 0; it < 31; ++it) {
        ktile(ic<0>{}, bc<true>{}, bc<true>{}, bc<true>{},
              ic<8>{}, ic<4>{}, ic<BK>{}, ic<2 * BK>{});
        ktile(ic<1>{}, bc<true>{}, bc<true>{}, bc<true>{},
              ic<8>{}, ic<4>{}, ic<2 * BK>{}, ic<3 * BK>{});
        aT += 2 * BK;
        bT += 2 * BK;
    }
    // tile 62: stage A1,B1(63) only; vmcnt(4)@p1 drains A0,B0(63) [from 61.p1];
    // vmcnt(0)@p3 drains A1,B1(63) for tile 63's reads.
    ktile(ic<0>{}, bc<true>{}, bc<false>{}, bc<true>{},
          ic<4>{}, ic<0>{}, ic<BK>{}, ic<0>{});
    // tile 63: no stages, no cross-tile reads, no waits
    ktile(ic<1>{}, bc<false>{}, bc<false>{}, bc<false>{},
          ic<-1>{}, ic<-1>{}, ic<0>{}, ic<0>{});

    #undef MFMA_CLUSTER

    // epilogue: C/D layout col = lane&15 (out-dim), row = (lane>>4)*4 + rr (M)
    #pragma unroll
    for (int mh_ = 0; mh_ < 2; ++mh_)
        #pragma unroll
        for (int j = 0; j < 4; ++j)
            #pragma unroll
            for (int rr = 0; rr < 4; ++rr) {
                const int row = bm * BM + mh_ * 128 + j * 32 + wm * 16 + ((lane >> 4) << 2) + rr;
                float* orow = out + (size_t)row * K_TOT;
                #pragma unroll
                for (int nh_ = 0; nh_ < 2; ++nh_)
                    #pragma unroll
                    for (int j2 = 0; j2 < 2; ++j2) {
                        const int col = bn * BN + nh_ * 128 + j2 * 64 + wn * 16 + (lane & 15);
                        orow[col] = acc[mh_][nh_][j][j2][rr] + bias[col];
                    }
            }
}

extern "C" void kernel_launch(void* const* d_in, const int* in_sizes, int n_in,
                              void* d_out, int out_size, void* d_ws, size_t ws_size,
                              hipStream_t stream) {
    const float* x      = (const float*)d_in[0];
    const float* scales = (const float*)d_in[1];
    const float* zeros  = (const float*)d_in[2];
    const float* mu1    = (const float*)d_in[3];
    const float* mu2    = (const float*)d_in[4];
    const float* bias   = (const float*)d_in[5];
    const int*   wq     = (const int*)d_in[6];
    float* out = (float*)d_out;

    u16* xb = (u16*)d_ws;                                 // 64 MiB
    u16* wb = (u16*)d_ws + (size_t)M_TOT * N_TOT;         // 32 MiB

    cvt_x_kernel<<<(M_TOT * N_TOT / 8) / 256, 256, 0, stream>>>(x, xb);
    deq_w_kernel<<<(K_TOT * N_TOT / 8) / 256, 256, 0, stream>>>(wq, scales, zeros, mu1, mu2, wb);
    gemm_kernel<<<(M_TOT / BM) * (K_TOT / BN), 512, 0, stream>>>(xb, wb, bias, out);
}

// Round 11
// 265.511 us; speedup vs baseline: 13.8698x; 1.0977x over previous
//
#include <hip/hip_runtime.h>
#include <hip/hip_bf16.h>
#include <stdint.h>
#include <type_traits>

typedef unsigned short u16;
typedef __bf16 bf16x8 __attribute__((ext_vector_type(8)));
typedef float f32x4 __attribute__((ext_vector_type(4)));

#define M_TOT 8192   // B*S
#define N_TOT 4096   // reduction dim
#define K_TOT 4096   // output dim
#define BM 256
#define BN 256
#define BK 64
#define NT 64        // N_TOT / BK

// LDS geometry in u16 elements: [slot][A:2 halves | B:2 halves][128][64]
#define HALF_EL 8192     // 128 rows * 64 cols
#define B_OFF   16384
#define SLOT_EL 32768    // 64 KiB per slot
#define SLOT_BYTES 65536

template <int V> using ic = std::integral_constant<int, V>;
template <bool V> using bc = std::integral_constant<bool, V>;

__device__ __forceinline__ u16 f2bf(float f) {
    union { float f; uint32_t u; } v; v.f = f;
    uint32_t u = v.u;
    return (u16)((u + 0x7fffu + ((u >> 16) & 1u)) >> 16);
}

// ---- pre-pass 1: x fp32 -> bf16 ----------------------------------------------
__global__ __launch_bounds__(256) void cvt_x_kernel(const float* __restrict__ x,
                                                    u16* __restrict__ xb) {
    const int i = blockIdx.x * blockDim.x + threadIdx.x;
    const float4* p = (const float4*)x + (size_t)i * 2;
    float4 v0 = p[0], v1 = p[1];
    uint4 o;
    o.x = (uint32_t)f2bf(v0.x) | ((uint32_t)f2bf(v0.y) << 16);
    o.y = (uint32_t)f2bf(v0.z) | ((uint32_t)f2bf(v0.w) << 16);
    o.z = (uint32_t)f2bf(v1.x) | ((uint32_t)f2bf(v1.y) << 16);
    o.w = (uint32_t)f2bf(v1.z) | ((uint32_t)f2bf(v1.w) << 16);
    *((uint4*)(xb + (size_t)i * 8)) = o;
}

// ---- pre-pass 2: dequantize W_q -> bf16 --------------------------------------
__global__ __launch_bounds__(256) void deq_w_kernel(const int* __restrict__ wq,
                                                    const float* __restrict__ scales,
                                                    const float* __restrict__ zeros,
                                                    const float* __restrict__ mu1,
                                                    const float* __restrict__ mu2,
                                                    u16* __restrict__ wb) {
    const int i = blockIdx.x * blockDim.x + threadIdx.x;
    const int k  = i >> 9;
    const int n0 = (i & 511) << 3;
    const int g  = n0 >> 6;
    const float z  = zeros[k * 64 + g];
    const float sm = scales[k * 64 + g] * mu2[k];
    const int4* qp = (const int4*)(wq + (size_t)k * N_TOT + n0);
    int4 q0 = qp[0], q1 = qp[1];
    const float4* mp = (const float4*)(mu1 + n0);
    float4 u0 = mp[0], u1 = mp[1];
    uint4 o;
    o.x = (uint32_t)f2bf(((float)q0.x - z) * sm * u0.x) |
          ((uint32_t)f2bf(((float)q0.y - z) * sm * u0.y) << 16);
    o.y = (uint32_t)f2bf(((float)q0.z - z) * sm * u0.z) |
          ((uint32_t)f2bf(((float)q0.w - z) * sm * u0.w) << 16);
    o.z = (uint32_t)f2bf(((float)q1.x - z) * sm * u1.x) |
          ((uint32_t)f2bf(((float)q1.y - z) * sm * u1.y) << 16);
    o.w = (uint32_t)f2bf(((float)q1.z - z) * sm * u1.z) |
          ((uint32_t)f2bf(((float)q1.w - z) * sm * u1.w) << 16);
    *((uint4*)(wb + (size_t)k * N_TOT + n0)) = o;
}

// ---- main GEMM: one-ahead continuous-feed, NO explicit lgkm, 2 barriers/tile --
// 8 waves (2M x 4N), per-wave out 128x64, BK=64, double-buffered LDS.
// Quadrants: q0=(A0,B0) q1=(A0,B1) q2=(A1,B1) q3=(A1,B0).
// Frag groups afLo/afHi/bf0/bf1 = 96 VGPR max-concurrent; each refill
// overwrites a just-dead group. ONE-AHEAD: every read's consumer MFMA sits
// >=1 full cluster later; the COMPILER places counted lgkm waits there, so
// the LDS pipe stays fed underneath MFMA clusters. No explicit lgkm anywhere.
//   p0: read bf1(t)       ; stage A1,B1(t+1)->S^1 ; MFMA q0(afLo,bf0)
//   p1: read afHi(t)      ;                       ; MFMA q1(afLo,bf1)
//       vmcnt(4) ; barrier ; sched_barrier
//   p2: read afLo(t+1)@S^1; stage A0,B0(t+2)->S   ; MFMA q2(afHi,bf1)
//   p3: MFMA q3(afHi,bf0) ; read bf0(t+1)@S^1
//       vmcnt(4) ; barrier ; sched_barrier
// vmcnt derivation: at p1-end outstanding = {t-1.p2: A0B0(t+1)}(4) +
//   {t.p0: A1B1(t+1)}(4) -> vmcnt(4) drains t-1.p2, needed by p2's afLo read.
//   At p3-end outstanding = {t.p0}(4) + {t.p2: A0B0(t+2)}(4) -> vmcnt(4)
//   drains t.p0 = A1B1(t+1), needed by t+1.p0/p1 reads. 3-phase flight > HBM.
// WAR legality: stage A1B1->S^1 @p0: that region's last reads (afHi/bf1 of
//   t-1) were consumed by t-1's q2/q3 MFMAs BEFORE t-1's p3-end barrier.
//   Stage A0B0->S @p2: afLo/bf0(t) consumed by q0/q1 BEFORE t's p1-end
//   barrier. Race-sensitive reads all follow an asm-"memory" vmcnt -> cannot
//   hoist. LDS read bases = 4 toggling 32-bit byte-offsets (^=65536/tile).
// LDS XOR swizzle (proven R2): physical col = logical ^ ((row&7)*8 elems).
__global__ __launch_bounds__(512, 2) void gemm_kernel(const u16* __restrict__ Xb,
                                                      const u16* __restrict__ Wb,
                                                      const float* __restrict__ bias,
                                                      float* __restrict__ out) {
    __shared__ __align__(16) u16 lds[2 * SLOT_EL];   // 128 KiB

    // XCD-bijective swizzle: nwg = 512, divisible by 8
    const int bid = blockIdx.x;
    const int cpx = gridDim.x >> 3;
    const int swz = (bid & 7) * cpx + (bid >> 3);
    const int bm = swz >> 4;    // 32 M-tiles
    const int bn = swz & 15;    // 16 out-tiles

    const int tid  = threadIdx.x;
    const int w    = tid >> 6;
    const int lane = tid & 63;
    const int wm = w >> 2, wn = w & 3;

    // staging: lane l, issue i covers LDS row (w*16 + i*8 + (l>>3)), physical
    // col (l&7)*16B; global col pre-swizzled: ((l&7)^(l>>3))*8 elems.
    const int scol = (((lane & 7) ^ (lane >> 3)) << 3);
    const u16* aT = Xb + (size_t)(bm * BM + w * 16 + (lane >> 3)) * N_TOT + scol;
    const u16* bT = Wb + (size_t)(bn * BN + w * 16 + (lane >> 3)) * N_TOT + scol;

    u16* const sdA = &lds[w * 1024];
    u16* const sdB = &lds[B_OFF + w * 1024];

    auto gload = [](const u16* s, u16* d) {
        __builtin_amdgcn_global_load_lds(
            (const __attribute__((address_space(1))) uint32_t*)s,
            (__attribute__((address_space(3))) uint32_t*)d, 16, 0, 0);
    };
    auto stA = [&](auto SlC, auto Hc, auto Dc) {
        const u16* s = aT + (size_t)(Hc.value * 128) * N_TOT + Dc.value;
        u16* d = sdA + SlC.value * SLOT_EL + Hc.value * HALF_EL;
        gload(s, d); gload(s + (size_t)8 * N_TOT, d + 512);
    };
    auto stB = [&](auto SlC, auto Hc, auto Dc) {
        const u16* s = bT + (size_t)(Hc.value * 128) * N_TOT + Dc.value;
        u16* d = sdB + SlC.value * SLOT_EL + Hc.value * HALF_EL;
        gload(s, d); gload(s + (size_t)8 * N_TOT, d + 512);
    };

    // toggling LDS read byte-offsets (current slot); ks0/ks1 variants
    const int cc0 = (((lane >> 4) << 3)) ^ ((lane & 7) << 3);
    const int rA  = ((wm << 4) + (lane & 15)) << 6;
    const int rB  = ((wn << 4) + (lane & 15)) << 6;
    int oAa = (rA + cc0) * 2;
    int oAb = (rA + (cc0 ^ 32)) * 2;
    int oBa = (B_OFF + rB + cc0) * 2;
    int oBb = (B_OFF + rB + (cc0 ^ 32)) * 2;
    const char* const ldsc = (const char*)lds;

    f32x4 acc[2][2][4][2] = {};
    bf16x8 afLo[4][2], afHi[4][2];   // [j][ks]
    bf16x8 bf0[2][2], bf1[2][2];     // [j2][ks]

    auto rd_afLo_next = [&]() {   // A half0 of NEXT tile (other slot)
        const int xa = oAa ^ SLOT_BYTES, xb2 = oAb ^ SLOT_BYTES;
        #pragma unroll
        for (int j = 0; j < 4; ++j) {
            afLo[j][0] = *(const bf16x8*)(ldsc + xa + j * 4096);
            afLo[j][1] = *(const bf16x8*)(ldsc + xb2 + j * 4096);
        }
    };
    auto rd_bf0_next = [&]() {    // B half0 of NEXT tile (other slot)
        const int xa = oBa ^ SLOT_BYTES, xb2 = oBb ^ SLOT_BYTES;
        #pragma unroll
        for (int j2 = 0; j2 < 2; ++j2) {
            bf0[j2][0] = *(const bf16x8*)(ldsc + xa + j2 * 8192);
            bf0[j2][1] = *(const bf16x8*)(ldsc + xb2 + j2 * 8192);
        }
    };
    auto rd_afHi_cur = [&]() {    // A half1 of CURRENT tile
        #pragma unroll
        for (int j = 0; j < 4; ++j) {
            afHi[j][0] = *(const bf16x8*)(ldsc + oAa + 16384 + j * 4096);
            afHi[j][1] = *(const bf16x8*)(ldsc + oAb + 16384 + j * 4096);
        }
    };
    auto rd_bf1_cur = [&]() {     // B half1 of CURRENT tile
        #pragma unroll
        for (int j2 = 0; j2 < 2; ++j2) {
            bf1[j2][0] = *(const bf16x8*)(ldsc + oBa + 16384 + j2 * 8192);
            bf1[j2][1] = *(const bf16x8*)(ldsc + oBb + 16384 + j2 * 8192);
        }
    };

    #define MFMA_CLUSTER(A, B, MH, NH)                                          \
        __builtin_amdgcn_s_setprio(1);                                          \
        _Pragma("unroll")                                                       \
        for (int ks = 0; ks < 2; ++ks)                                          \
            _Pragma("unroll")                                                   \
            for (int j = 0; j < 4; ++j)                                         \
                _Pragma("unroll")                                               \
                for (int j2 = 0; j2 < 2; ++j2)                                  \
                    acc[MH][NH][j][j2] = __builtin_amdgcn_mfma_f32_16x16x32_bf16(\
                        A[j][ks], B[j2][ks], acc[MH][NH][j][j2], 0, 0, 0);      \
        __builtin_amdgcn_s_setprio(0);

    // one K-tile. SL: slot parity (for stage dests / source deltas only).
    // St0: stage A1B1(t+1) @p0. St2: stage A0B0(t+2) @p2. RdN: ahead-reads.
    // V1/V3: counted vmcnt at the two sync points (-1 = skip wait+barrier pair
    // kept for structure; tail uses 0).
    auto ktile = [&](auto SlC, auto St0, auto St2, auto RdN,
                     auto V1c, auto V3c, auto D0, auto D1) {
        constexpr int SL = SlC.value;
        // ---- p0 ----
        rd_bf1_cur();
        if constexpr (St0.value) { stA(ic<SL ^ 1>{}, ic<1>{}, D0);
                                   stB(ic<SL ^ 1>{}, ic<1>{}, D0); }
        MFMA_CLUSTER(afLo, bf0, 0, 0)
        // ---- p1 ----
        rd_afHi_cur();
        MFMA_CLUSTER(afLo, bf1, 0, 1)
        if constexpr (V1c.value == 4) asm volatile("s_waitcnt vmcnt(4)" ::: "memory");
        else if constexpr (V1c.value == 0) asm volatile("s_waitcnt vmcnt(0)" ::: "memory");
        __builtin_amdgcn_s_barrier();
        __builtin_amdgcn_sched_barrier(0);
        // ---- p2 ----
        if constexpr (RdN.value) rd_afLo_next();
        if constexpr (St2.value) { stA(SlC, ic<0>{}, D1);
                                   stB(SlC, ic<0>{}, D1); }
        MFMA_CLUSTER(afHi, bf1, 1, 1)
        // ---- p3 ----
        MFMA_CLUSTER(afHi, bf0, 1, 0)
        if constexpr (RdN.value) rd_bf0_next();
        if constexpr (V3c.value == 4) asm volatile("s_waitcnt vmcnt(4)" ::: "memory");
        else if constexpr (V3c.value == 0) asm volatile("s_waitcnt vmcnt(0)" ::: "memory");
        __builtin_amdgcn_s_barrier();
        __builtin_amdgcn_sched_barrier(0);
        // toggle read bases to the other slot
        oAa ^= SLOT_BYTES; oAb ^= SLOT_BYTES; oBa ^= SLOT_BYTES; oBb ^= SLOT_BYTES;
    };

    // prologue: stage tile0 full (8) + A0,B0(tile1) (4 = the steady "t-1.p2"
    // residue); vmcnt(4) drains tile0; barrier; read q0 frags of tile0.
    stA(ic<0>{}, ic<0>{}, ic<0>{});  stB(ic<0>{}, ic<0>{}, ic<0>{});
    stA(ic<0>{}, ic<1>{}, ic<0>{});  stB(ic<0>{}, ic<1>{}, ic<0>{});
    stA(ic<1>{}, ic<0>{}, ic<BK>{}); stB(ic<1>{}, ic<0>{}, ic<BK>{});
    asm volatile("s_waitcnt vmcnt(4)" ::: "memory");
    __builtin_amdgcn_s_barrier();
    __builtin_amdgcn_sched_barrier(0);
    {   // initial q0 fragments from slot 0 (bases currently at slot 0)
        #pragma unroll
        for (int j = 0; j < 4; ++j) {
            afLo[j][0] = *(const bf16x8*)(ldsc + oAa + j * 4096);
            afLo[j][1] = *(const bf16x8*)(ldsc + oAb + j * 4096);
        }
        #pragma unroll
        for (int j2 = 0; j2 < 2; ++j2) {
            bf0[j2][0] = *(const bf16x8*)(ldsc + oBa + j2 * 8192);
            bf0[j2][1] = *(const bf16x8*)(ldsc + oBb + j2 * 8192);
        }
    }

    // steady: 31 pairs = tiles 0..61
    for (int it = 0; it < 31; ++it) {
        ktile(ic<0>{}, bc<true>{}, bc<true>{}, bc<true>{},
              ic<4>{}, ic<4>{}, ic<BK>{}, ic<2 * BK>{});
        ktile(ic<1>{}, bc<true>{}, bc<true>{}, bc<true>{},
              ic<4>{}, ic<4>{}, ic<2 * BK>{}, ic<3 * BK>{});
        aT += 2 * BK;
        bT += 2 * BK;
    }
    // tile 62: stage A1B1(63) @p0 only; V1=4 drains A0B0(63) [from 61.p2];
    // V3=0 drains A1B1(63) before tile 63's reads.
    ktile(ic<0>{}, bc<true>{}, bc<false>{}, bc<true>{},
          ic<4>{}, ic<0>{}, ic<BK>{}, ic<0>{});
    // tile 63: no stages, no ahead-reads, no waits
    ktile(ic<1>{}, bc<false>{}, bc<false>{}, bc<false>{},
          ic<-1>{}, ic<-1>{}, ic<0>{}, ic<0>{});

    #undef MFMA_CLUSTER

    // epilogue: C/D layout col = lane&15 (out-dim), row = (lane>>4)*4 + rr (M)
    #pragma unroll
    for (int mh_ = 0; mh_ < 2; ++mh_)
        #pragma unroll
        for (int j = 0; j < 4; ++j)
            #pragma unroll
            for (int rr = 0; rr < 4; ++rr) {
                const int row = bm * BM + mh_ * 128 + j * 32 + wm * 16 + ((lane >> 4) << 2) + rr;
                float* orow = out + (size_t)row * K_TOT;
                #pragma unroll
                for (int nh_ = 0; nh_ < 2; ++nh_)
                    #pragma unroll
                    for (int j2 = 0; j2 < 2; ++j2) {
                        const int col = bn * BN + nh_ * 128 + j2 * 64 + wn * 16 + (lane & 15);
                        orow[col] = acc[mh_][nh_][j][j2][rr] + bias[col];
                    }
            }
}

extern "C" void kernel_launch(void* const* d_in, const int* in_sizes, int n_in,
                              void* d_out, int out_size, void* d_ws, size_t ws_size,
                              hipStream_t stream) {
    const float* x      = (const float*)d_in[0];
    const float* scales = (const float*)d_in[1];
    const float* zeros  = (const float*)d_in[2];
    const float* mu1    = (const float*)d_in[3];
    const float* mu2    = (const float*)d_in[4];
    const float* bias   = (const float*)d_in[5];
    const int*   wq     = (const int*)d_in[6];
    float* out = (float*)d_out;

    u16* xb = (u16*)d_ws;                                 // 64 MiB
    u16* wb = (u16*)d_ws + (size_t)M_TOT * N_TOT;         // 32 MiB

    cvt_x_kernel<<<(M_TOT * N_TOT / 8) / 256, 256, 0, stream>>>(x, xb);
    deq_w_kernel<<<(K_TOT * N_TOT / 8) / 256, 256, 0, stream>>>(wq, scales, zeros, mu1, mu2, wb);
    gemm_kernel<<<(M_TOT / BM) * (K_TOT / BN), 512, 0, stream>>>(xb, wb, bias, out);
}